// Round 15
// baseline (180.788 us; speedup 1.0000x reference)
//
#include <hip/hip_runtime.h>
#include <hip/hip_bf16.h>
#include <math.h>

#define B_  8
#define T_  2048
#define E_  1024
#define H_  128
#define BT_ (B_*T_)
#define TH_ (T_*H_)

typedef unsigned short u16;
typedef __attribute__((ext_vector_type(8))) unsigned short u16x8;  // 16B
typedef __attribute__((ext_vector_type(8))) short bf16x8;          // MFMA A/B frag
typedef __attribute__((ext_vector_type(4))) float f32x4;           // MFMA C/D frag

__device__ __forceinline__ u16 f2bf(float f) {
    union { float f; unsigned int u; } a;
    a.f = f;
    unsigned int r = a.u + 0x7FFFu + ((a.u >> 16) & 1u);   // RNE
    return (u16)(r >> 16);
}

// ---------------------------------------------------------------------------
// prep: W[e][h] fp32  ->  Wt[w][h][e] bf16   (verified round 5)
// ---------------------------------------------------------------------------
__global__ __launch_bounds__(256) void prep_kernel(
    const float* __restrict__ Wk,
    const float* __restrict__ Wq,
    const float* __restrict__ Wv,
    u16* __restrict__ Wt)
{
    __shared__ u16 Tl[128][136];

    const int w  = blockIdx.x >> 3;
    const int et = blockIdx.x & 7;
    const float* __restrict__ W = (w == 0) ? Wk : (w == 1) ? Wq : Wv;
    const int tid = threadIdx.x;

    #pragma unroll
    for (int i = 0; i < 16; ++i) {
        int q = tid + i * 256;
        int e = q >> 5, hc = q & 31;
        float4 v = *reinterpret_cast<const float4*>(
            &W[(size_t)(et * 128 + e) * H_ + hc * 4]);
        Tl[hc * 4 + 0][e] = f2bf(v.x);
        Tl[hc * 4 + 1][e] = f2bf(v.y);
        Tl[hc * 4 + 2][e] = f2bf(v.z);
        Tl[hc * 4 + 3][e] = f2bf(v.w);
    }
    __syncthreads();

    #pragma unroll
    for (int i = 0; i < 8; ++i) {
        int q = tid + i * 256;
        int h = q >> 4, ec = q & 15;
        *reinterpret_cast<u16x8*>(
            &Wt[(size_t)w * (H_ * E_) + (size_t)h * E_ + et * 128 + ec * 8]) =
            *reinterpret_cast<const u16x8*>(&Tl[h][ec * 8]);
    }
}

// ---------------------------------------------------------------------------
// proj_mfma: out[t][h] = x[t][:] . W[:,h]  via bf16 MFMA (verified round 5)
// ---------------------------------------------------------------------------
__global__ __launch_bounds__(256) void proj_mfma(
    const float* __restrict__ x,
    const u16* __restrict__ Wt,
    u16* __restrict__ k_out,
    u16* __restrict__ q_out,
    u16* __restrict__ vt_out)
{
    __shared__ __align__(16) u16 S[13824];   // As[64][72] @0 | Bs[128][72] @4608
    u16* As = S;
    u16* Bs = S + 4608;

    const int row0 = blockIdx.x * 64;
    const int w    = blockIdx.z;
    const int tid  = threadIdx.x;
    const int wave = tid >> 6;
    const int lane = tid & 63;
    const int l15  = lane & 15;
    const int g    = lane >> 4;
    const int wm   = wave >> 1;
    const int wn   = wave & 1;

    f32x4 acc[2][4];
    #pragma unroll
    for (int m = 0; m < 2; ++m)
        #pragma unroll
        for (int n = 0; n < 4; ++n) acc[m][n] = (f32x4){0.f, 0.f, 0.f, 0.f};

    const u16* WtW = Wt + (size_t)w * (H_ * E_);

    for (int ek = 0; ek < 16; ++ek) {
        __syncthreads();
        #pragma unroll
        for (int i = 0; i < 4; ++i) {
            int q = tid + i * 256;
            int r = q >> 4, c4 = q & 15;
            float4 v = *reinterpret_cast<const float4*>(
                &x[(size_t)(row0 + r) * E_ + ek * 64 + c4 * 4]);
            ushort4 h4;
            h4.x = f2bf(v.x); h4.y = f2bf(v.y);
            h4.z = f2bf(v.z); h4.w = f2bf(v.w);
            *reinterpret_cast<ushort4*>(&As[r * 72 + c4 * 4]) = h4;
        }
        #pragma unroll
        for (int i = 0; i < 4; ++i) {
            int q = tid + i * 256;
            int h = q >> 3, c8 = q & 7;
            *reinterpret_cast<u16x8*>(&Bs[h * 72 + c8 * 8]) =
                *reinterpret_cast<const u16x8*>(
                    &WtW[(size_t)h * E_ + ek * 64 + c8 * 8]);
        }
        __syncthreads();

        #pragma unroll
        for (int kk = 0; kk < 2; ++kk) {
            bf16x8 af[2];
            #pragma unroll
            for (int m = 0; m < 2; ++m)
                af[m] = *reinterpret_cast<const bf16x8*>(
                    &As[(wm * 32 + m * 16 + l15) * 72 + kk * 32 + g * 8]);
            #pragma unroll
            for (int n = 0; n < 4; ++n) {
                bf16x8 bfr = *reinterpret_cast<const bf16x8*>(
                    &Bs[(wn * 64 + n * 16 + l15) * 72 + kk * 32 + g * 8]);
                #pragma unroll
                for (int m = 0; m < 2; ++m)
                    acc[m][n] = __builtin_amdgcn_mfma_f32_16x16x32_bf16(
                        af[m], bfr, acc[m][n], 0, 0, 0);
            }
        }
    }
    __syncthreads();

    if (w < 2) {
        #pragma unroll
        for (int m = 0; m < 2; ++m)
            #pragma unroll
            for (int n = 0; n < 4; ++n)
                #pragma unroll
                for (int r = 0; r < 4; ++r)
                    S[(wm * 32 + m * 16 + g * 4 + r) * 136 +
                      wn * 64 + n * 16 + l15] = f2bf(acc[m][n][r]);
        __syncthreads();
        u16* __restrict__ outp = (w == 0) ? k_out : q_out;
        #pragma unroll
        for (int i = 0; i < 4; ++i) {
            int q = tid + i * 256;
            int r = q >> 4, c8 = q & 15;
            *reinterpret_cast<u16x8*>(
                &outp[(size_t)(row0 + r) * H_ + c8 * 8]) =
                *reinterpret_cast<const u16x8*>(&S[r * 136 + c8 * 8]);
        }
    } else {
        #pragma unroll
        for (int m = 0; m < 2; ++m)
            #pragma unroll
            for (int n = 0; n < 4; ++n) {
                ushort4 h4;
                h4.x = f2bf(acc[m][n][0]); h4.y = f2bf(acc[m][n][1]);
                h4.z = f2bf(acc[m][n][2]); h4.w = f2bf(acc[m][n][3]);
                *reinterpret_cast<ushort4*>(
                    &S[(wn * 64 + n * 16 + l15) * 72 +
                       wm * 32 + m * 16 + g * 4]) = h4;
            }
        __syncthreads();
        const int vb = row0 >> 11;
        const int t0 = row0 & 2047;
        #pragma unroll
        for (int i = 0; i < 4; ++i) {
            int q = tid + i * 256;
            int h = q >> 3, c8 = q & 7;
            *reinterpret_cast<u16x8*>(
                &vt_out[(size_t)vb * TH_ + (size_t)h * T_ + t0 + c8 * 8]) =
                *reinterpret_cast<const u16x8*>(&S[h * 72 + c8 * 8]);
        }
    }
}

// ---------------------------------------------------------------------------
// Flash attention, bf16 MFMA — round-14 tile loop (32 q-rows/wave, asm-batched
// VMEM + counted vmcnt, balanced CU pairing) with 8-WAY s-split per block:
// block = 512 thr (8 waves) -> 2 blocks/CU = 16 waves/CU = 4 waves/SIMD
// (was 2/SIMD). Merge overlay shrunk via ht-half passes so LDS pool = 67.6 KB
// (2 resident). __launch_bounds__(512,4) caps VGPR at 128 (loop used 124).
// grid: 512 = 8 batches (low bits, XCD affinity) x 64 row-tiles, paired so
// co-resident blocks sum to 33 tile-units.
// ---------------------------------------------------------------------------
__global__ __launch_bounds__(512, 4) void attn_mfma(
    const u16* __restrict__ qg,
    const u16* __restrict__ kg,
    const u16* __restrict__ vtg,
    float* __restrict__ out)
{
    // Pool: loop phase  = Plds u16[8][32][72]             = 36864 B
    //       merge phase = Om f32[512][17] (34816 B) @0
    //                   + Ms f32[512][8]  (16384 B) @34816
    //                   + Ls f32[512][8]  (16384 B) @51200  -> 67584 B
    __shared__ __align__(16) unsigned char Pool[67584];
    u16 (*Plds)[32][72] = reinterpret_cast<u16 (*)[32][72]>(Pool);

    const int tid  = threadIdx.x;
    const int wave = tid >> 6;           // 0..7
    const int lane = tid & 63;
    const int l15  = lane & 15;
    const int g    = lane >> 4;          // 0..3

    const int b   = blockIdx.x & 7;              // batch -> XCD affinity
    const int p   = blockIdx.x >> 3;             // 0..63
    const int jt  = (p < 32) ? (63 - p) : (p - 32);  // balanced CU pairing
    const int qw0 = jt * 32;                     // block's 32 q rows
    const size_t gbase = (size_t)b * TH_;

    // Q fragments: 2 row-fragments x 4 k-steps (same rows for all 8 waves)
    bf16x8 qf[2][4];
    #pragma unroll
    for (int m = 0; m < 2; ++m)
        #pragma unroll
        for (int ks = 0; ks < 4; ++ks)
            qf[m][ks] = *reinterpret_cast<const bf16x8*>(
                &qg[gbase + (size_t)(qw0 + m * 16 + l15) * H_ + ks * 32 + g * 8]);

    f32x4 oacc[2][8];
    #pragma unroll
    for (int m = 0; m < 2; ++m)
        #pragma unroll
        for (int ht = 0; ht < 8; ++ht) oacc[m][ht] = (f32x4){0.f, 0.f, 0.f, 0.f};
    float m_r[2][4], lsum[2][4];
    #pragma unroll
    for (int m = 0; m < 2; ++m)
        #pragma unroll
        for (int r = 0; r < 4; ++r) { m_r[m][r] = -INFINITY; lsum[m][r] = 0.f; }

    const u16* kbat  = kg  + gbase;
    const u16* vtbat = vtg + gbase;

    const int nt = (jt >> 1) + 1;        // causal s-tiles for this row-tile
    for (int st = wave; st < nt; st += 8) {
        const int s0 = st * 64;
        const u16* kp = kbat + (size_t)s0 * H_;

        // ---- batch-issue 16 K loads via asm (back-to-back, no interleaved waits)
        bf16x8 kf[4][4];
        #pragma unroll
        for (int ks = 0; ks < 4; ++ks)
            #pragma unroll
            for (int t4 = 0; t4 < 4; ++t4) {
                const u16* pk = &kp[(size_t)(t4 * 16 + l15) * H_ + (ks * 4 + g) * 8];
                asm volatile("global_load_dwordx4 %0, %1, off"
                             : "=v"(kf[ks][t4]) : "v"(pk));
            }
        asm volatile("s_waitcnt vmcnt(0)" ::: "memory");
        __builtin_amdgcn_sched_barrier(0);

        // ---- QK^T: 32 MFMA (2 m x 4 ks x 4 t4), K reused across m ----
        f32x4 sa[2][4];
        #pragma unroll
        for (int m = 0; m < 2; ++m)
            #pragma unroll
            for (int t4 = 0; t4 < 4; ++t4) sa[m][t4] = (f32x4){0.f, 0.f, 0.f, 0.f};
        __builtin_amdgcn_s_setprio(1);
        #pragma unroll
        for (int ks = 0; ks < 4; ++ks)
            #pragma unroll
            for (int t4 = 0; t4 < 4; ++t4)
                #pragma unroll
                for (int m = 0; m < 2; ++m)
                    sa[m][t4] = __builtin_amdgcn_mfma_f32_16x16x32_bf16(
                        qf[m][ks], kf[ks][t4], sa[m][t4], 0, 0, 0);
        __builtin_amdgcn_s_setprio(0);

        // ---- batch-issue 16 V loads via asm (V0 then V1); fly under softmax --
        bf16x8 vf0[8], vf1[8];
        #pragma unroll
        for (int ht = 0; ht < 8; ++ht) {
            const u16* pv = &vtbat[(size_t)(ht * 16 + l15) * T_ + s0 + g * 8];
            asm volatile("global_load_dwordx4 %0, %1, off"
                         : "=v"(vf0[ht]) : "v"(pv));
        }
        #pragma unroll
        for (int ht = 0; ht < 8; ++ht) {
            const u16* pv = &vtbat[(size_t)(ht * 16 + l15) * T_ + s0 + (4 + g) * 8];
            asm volatile("global_load_dwordx4 %0, %1, off"
                         : "=v"(vf1[ht]) : "v"(pv));
        }

        // ---- online softmax over 8 rows/lane (2 m x 4 r) ----
        const float scale = 0.088388347648318447f;   // 1/sqrt(128)
        const bool need_mask = (s0 + 63 > qw0);
        float cfac[2][4];
        #pragma unroll
        for (int m = 0; m < 2; ++m) {
            #pragma unroll
            for (int r = 0; r < 4; ++r) {
                const int qrow = qw0 + m * 16 + g * 4 + r;
                float sv[4];
                float mx = -INFINITY;
                #pragma unroll
                for (int t4 = 0; t4 < 4; ++t4) {
                    float s = sa[m][t4][r] * scale;
                    if (need_mask && (s0 + t4 * 16 + l15 > qrow)) s = -INFINITY;
                    sv[t4] = s;
                    mx = fmaxf(mx, s);
                }
                mx = fmaxf(mx, __shfl_xor(mx, 1));
                mx = fmaxf(mx, __shfl_xor(mx, 2));
                mx = fmaxf(mx, __shfl_xor(mx, 4));
                mx = fmaxf(mx, __shfl_xor(mx, 8));
                const float mn = fmaxf(m_r[m][r], mx);
                const float c  = __expf(m_r[m][r] - mn);
                float sum = 0.f;
                #pragma unroll
                for (int t4 = 0; t4 < 4; ++t4) {
                    float pv = __expf(sv[t4] - mn);
                    sum += pv;
                    Plds[wave][m * 16 + g * 4 + r][t4 * 16 + l15] = f2bf(pv);
                }
                sum += __shfl_xor(sum, 1);
                sum += __shfl_xor(sum, 2);
                sum += __shfl_xor(sum, 4);
                sum += __shfl_xor(sum, 8);
                lsum[m][r] = lsum[m][r] * c + sum;
                m_r[m][r]  = mn;
                cfac[m][r] = c;
            }
        }

        // ---- rescale O ----
        #pragma unroll
        for (int m = 0; m < 2; ++m)
            #pragma unroll
            for (int ht = 0; ht < 8; ++ht)
                #pragma unroll
                for (int r = 0; r < 4; ++r) oacc[m][ht][r] *= cfac[m][r];

        // ---- PV half 0: wait V0 only (vmcnt(8) keeps V1 outstanding) ----
        asm volatile("s_waitcnt vmcnt(8)" ::: "memory");
        __builtin_amdgcn_sched_barrier(0);
        #pragma unroll
        for (int m = 0; m < 2; ++m) {
            bf16x8 pa = *reinterpret_cast<const bf16x8*>(
                &Plds[wave][m * 16 + l15][g * 8]);
            __builtin_amdgcn_s_setprio(1);
            #pragma unroll
            for (int ht = 0; ht < 8; ++ht)
                oacc[m][ht] = __builtin_amdgcn_mfma_f32_16x16x32_bf16(
                    pa, vf0[ht], oacc[m][ht], 0, 0, 0);
            __builtin_amdgcn_s_setprio(0);
        }
        // ---- PV half 1 ----
        asm volatile("s_waitcnt vmcnt(0)" ::: "memory");
        __builtin_amdgcn_sched_barrier(0);
        #pragma unroll
        for (int m = 0; m < 2; ++m) {
            bf16x8 pa = *reinterpret_cast<const bf16x8*>(
                &Plds[wave][m * 16 + l15][32 + g * 8]);
            __builtin_amdgcn_s_setprio(1);
            #pragma unroll
            for (int ht = 0; ht < 8; ++ht)
                oacc[m][ht] = __builtin_amdgcn_mfma_f32_16x16x32_bf16(
                    pa, vf1[ht], oacc[m][ht], 0, 0, 0);
            __builtin_amdgcn_s_setprio(0);
        }
    }

    // ---- block-wide 8-partial split-s merge, 2 m x 2 ht-half passes ----
    __syncthreads();                      // all waves done with Plds -> pool reuse
    {
        float* Om = reinterpret_cast<float*>(Pool);           // [512][17]
        float* Ms = reinterpret_cast<float*>(Pool + 34816);   // [512][8]
        float* Ls = reinterpret_cast<float*>(Pool + 51200);   // [512][8]
        const int wl = wave * 64 + lane;
        #pragma unroll
        for (int m = 0; m < 2; ++m)
            #pragma unroll
            for (int r = 0; r < 4; ++r) {
                Ms[wl * 8 + m * 4 + r] = m_r[m][r];
                Ls[wl * 8 + m * 4 + r] = lsum[m][r];
            }

        #pragma unroll
        for (int m = 0; m < 2; ++m) {
            float Mr[4], inv[4], wgt[8][4];   // wave0's merge state (persists
                                              // across the two ht-half passes)
            #pragma unroll
            for (int hh = 0; hh < 2; ++hh) {
                #pragma unroll
                for (int h4 = 0; h4 < 4; ++h4)
                    #pragma unroll
                    for (int r = 0; r < 4; ++r)
                        Om[wl * 17 + h4 * 4 + r] = oacc[m][hh * 4 + h4][r];
                __syncthreads();

                if (wave == 0) {
                    if (hh == 0) {
                        #pragma unroll
                        for (int r = 0; r < 4; ++r) {
                            float M = -INFINITY;
                            #pragma unroll
                            for (int w2 = 0; w2 < 8; ++w2)
                                M = fmaxf(M, Ms[(w2 * 64 + lane) * 8 + m * 4 + r]);
                            float L = 0.f;
                            #pragma unroll
                            for (int w2 = 0; w2 < 8; ++w2) {
                                wgt[w2][r] = __expf(
                                    Ms[(w2 * 64 + lane) * 8 + m * 4 + r] - M);
                                L += Ls[(w2 * 64 + lane) * 8 + m * 4 + r] * wgt[w2][r];
                            }
                            Mr[r]  = M;
                            inv[r] = 1.f / L;
                        }
                    }
                    #pragma unroll
                    for (int r = 0; r < 4; ++r) {
                        float* op = &out[gbase +
                            (size_t)(qw0 + m * 16 + g * 4 + r) * H_];
                        #pragma unroll
                        for (int h4 = 0; h4 < 4; ++h4) {
                            float a = 0.f;
                            #pragma unroll
                            for (int w2 = 0; w2 < 8; ++w2)
                                a += Om[(w2 * 64 + lane) * 17 + h4 * 4 + r]
                                     * wgt[w2][r];
                            op[(hh * 4 + h4) * 16 + l15] = a * inv[r];
                        }
                    }
                }
                __syncthreads();          // wave0 done reading Om before overwrite
            }
            (void)Mr;
        }
    }
}

// ---------------------------------------------------------------------------
extern "C" void kernel_launch(void* const* d_in, const int* in_sizes, int n_in,
                              void* d_out, int out_size, void* d_ws, size_t ws_size,
                              hipStream_t stream) {
    const float* x  = (const float*)d_in[0];
    const float* Wk = (const float*)d_in[1];
    const float* Wq = (const float*)d_in[2];
    const float* Wv = (const float*)d_in[3];
    float* out = (float*)d_out;

    u16* k_ws  = (u16*)d_ws;
    u16* q_ws  = k_ws + (size_t)BT_ * H_;
    u16* vt_ws = q_ws + (size_t)BT_ * H_;
    u16* Wt_ws = vt_ws + (size_t)BT_ * H_;

    prep_kernel<<<dim3(24), 256, 0, stream>>>(Wk, Wq, Wv, Wt_ws);

    dim3 pgrid(BT_ / 64, 1, 3);    // z: 0=k, 1=q, 2=v^T
    proj_mfma<<<pgrid, 256, 0, stream>>>(x, Wt_ws, k_ws, q_ws, vt_ws);

    attn_mfma<<<dim3(512), 512, 0, stream>>>(q_ws, k_ws, vt_ws, out);
}

// Round 16
// 99.649 us; speedup vs baseline: 1.8143x; 1.8143x over previous
//
#include <hip/hip_runtime.h>
#include <hip/hip_bf16.h>
#include <math.h>

#define B_  8
#define T_  2048
#define E_  1024
#define H_  128
#define BT_ (B_*T_)
#define TH_ (T_*H_)

typedef unsigned short u16;
typedef __attribute__((ext_vector_type(8))) unsigned short u16x8;  // 16B
typedef __attribute__((ext_vector_type(8))) short bf16x8;          // MFMA A/B frag
typedef __attribute__((ext_vector_type(4))) float f32x4;           // MFMA C/D frag

__device__ __forceinline__ u16 f2bf(float f) {
    union { float f; unsigned int u; } a;
    a.f = f;
    unsigned int r = a.u + 0x7FFFu + ((a.u >> 16) & 1u);   // RNE
    return (u16)(r >> 16);
}

// ---------------------------------------------------------------------------
// prep: W[e][h] fp32  ->  Wt[w][h][e] bf16   (verified round 5)
// ---------------------------------------------------------------------------
__global__ __launch_bounds__(256) void prep_kernel(
    const float* __restrict__ Wk,
    const float* __restrict__ Wq,
    const float* __restrict__ Wv,
    u16* __restrict__ Wt)
{
    __shared__ u16 Tl[128][136];

    const int w  = blockIdx.x >> 3;
    const int et = blockIdx.x & 7;
    const float* __restrict__ W = (w == 0) ? Wk : (w == 1) ? Wq : Wv;
    const int tid = threadIdx.x;

    #pragma unroll
    for (int i = 0; i < 16; ++i) {
        int q = tid + i * 256;
        int e = q >> 5, hc = q & 31;
        float4 v = *reinterpret_cast<const float4*>(
            &W[(size_t)(et * 128 + e) * H_ + hc * 4]);
        Tl[hc * 4 + 0][e] = f2bf(v.x);
        Tl[hc * 4 + 1][e] = f2bf(v.y);
        Tl[hc * 4 + 2][e] = f2bf(v.z);
        Tl[hc * 4 + 3][e] = f2bf(v.w);
    }
    __syncthreads();

    #pragma unroll
    for (int i = 0; i < 8; ++i) {
        int q = tid + i * 256;
        int h = q >> 4, ec = q & 15;
        *reinterpret_cast<u16x8*>(
            &Wt[(size_t)w * (H_ * E_) + (size_t)h * E_ + et * 128 + ec * 8]) =
            *reinterpret_cast<const u16x8*>(&Tl[h][ec * 8]);
    }
}

// ---------------------------------------------------------------------------
// proj_mfma: out[t][h] = x[t][:] . W[:,h]  via bf16 MFMA (verified round 5)
// ---------------------------------------------------------------------------
__global__ __launch_bounds__(256) void proj_mfma(
    const float* __restrict__ x,
    const u16* __restrict__ Wt,
    u16* __restrict__ k_out,
    u16* __restrict__ q_out,
    u16* __restrict__ vt_out)
{
    __shared__ __align__(16) u16 S[13824];   // As[64][72] @0 | Bs[128][72] @4608
    u16* As = S;
    u16* Bs = S + 4608;

    const int row0 = blockIdx.x * 64;
    const int w    = blockIdx.z;
    const int tid  = threadIdx.x;
    const int wave = tid >> 6;
    const int lane = tid & 63;
    const int l15  = lane & 15;
    const int g    = lane >> 4;
    const int wm   = wave >> 1;
    const int wn   = wave & 1;

    f32x4 acc[2][4];
    #pragma unroll
    for (int m = 0; m < 2; ++m)
        #pragma unroll
        for (int n = 0; n < 4; ++n) acc[m][n] = (f32x4){0.f, 0.f, 0.f, 0.f};

    const u16* WtW = Wt + (size_t)w * (H_ * E_);

    for (int ek = 0; ek < 16; ++ek) {
        __syncthreads();
        #pragma unroll
        for (int i = 0; i < 4; ++i) {
            int q = tid + i * 256;
            int r = q >> 4, c4 = q & 15;
            float4 v = *reinterpret_cast<const float4*>(
                &x[(size_t)(row0 + r) * E_ + ek * 64 + c4 * 4]);
            ushort4 h4;
            h4.x = f2bf(v.x); h4.y = f2bf(v.y);
            h4.z = f2bf(v.z); h4.w = f2bf(v.w);
            *reinterpret_cast<ushort4*>(&As[r * 72 + c4 * 4]) = h4;
        }
        #pragma unroll
        for (int i = 0; i < 4; ++i) {
            int q = tid + i * 256;
            int h = q >> 3, c8 = q & 7;
            *reinterpret_cast<u16x8*>(&Bs[h * 72 + c8 * 8]) =
                *reinterpret_cast<const u16x8*>(
                    &WtW[(size_t)h * E_ + ek * 64 + c8 * 8]);
        }
        __syncthreads();

        #pragma unroll
        for (int kk = 0; kk < 2; ++kk) {
            bf16x8 af[2];
            #pragma unroll
            for (int m = 0; m < 2; ++m)
                af[m] = *reinterpret_cast<const bf16x8*>(
                    &As[(wm * 32 + m * 16 + l15) * 72 + kk * 32 + g * 8]);
            #pragma unroll
            for (int n = 0; n < 4; ++n) {
                bf16x8 bfr = *reinterpret_cast<const bf16x8*>(
                    &Bs[(wn * 64 + n * 16 + l15) * 72 + kk * 32 + g * 8]);
                #pragma unroll
                for (int m = 0; m < 2; ++m)
                    acc[m][n] = __builtin_amdgcn_mfma_f32_16x16x32_bf16(
                        af[m], bfr, acc[m][n], 0, 0, 0);
            }
        }
    }
    __syncthreads();

    if (w < 2) {
        #pragma unroll
        for (int m = 0; m < 2; ++m)
            #pragma unroll
            for (int n = 0; n < 4; ++n)
                #pragma unroll
                for (int r = 0; r < 4; ++r)
                    S[(wm * 32 + m * 16 + g * 4 + r) * 136 +
                      wn * 64 + n * 16 + l15] = f2bf(acc[m][n][r]);
        __syncthreads();
        u16* __restrict__ outp = (w == 0) ? k_out : q_out;
        #pragma unroll
        for (int i = 0; i < 4; ++i) {
            int q = tid + i * 256;
            int r = q >> 4, c8 = q & 15;
            *reinterpret_cast<u16x8*>(
                &outp[(size_t)(row0 + r) * H_ + c8 * 8]) =
                *reinterpret_cast<const u16x8*>(&S[r * 136 + c8 * 8]);
        }
    } else {
        #pragma unroll
        for (int m = 0; m < 2; ++m)
            #pragma unroll
            for (int n = 0; n < 4; ++n) {
                ushort4 h4;
                h4.x = f2bf(acc[m][n][0]); h4.y = f2bf(acc[m][n][1]);
                h4.z = f2bf(acc[m][n][2]); h4.w = f2bf(acc[m][n][3]);
                *reinterpret_cast<ushort4*>(
                    &S[(wn * 64 + n * 16 + l15) * 72 +
                       wm * 32 + m * 16 + g * 4]) = h4;
            }
        __syncthreads();
        const int vb = row0 >> 11;
        const int t0 = row0 & 2047;
        #pragma unroll
        for (int i = 0; i < 4; ++i) {
            int q = tid + i * 256;
            int h = q >> 3, c8 = q & 7;
            *reinterpret_cast<u16x8*>(
                &vt_out[(size_t)vb * TH_ + (size_t)h * T_ + t0 + c8 * 8]) =
                *reinterpret_cast<const u16x8*>(&S[h * 72 + c8 * 8]);
        }
    }
}

// ---------------------------------------------------------------------------
// Flash attention, bf16 MFMA — 8-way s-split per block, CORRECT VGPR cap:
// __launch_bounds__(512, 2) = 2 workgroups/CU x 8 waves = 16 waves/CU =
// 4 waves/SIMD -> VGPR cap 128 (loop needs ~124; round-15's (512,4) meant
// 4 wg/CU -> cap 64 -> catastrophic spill, WRITE_SIZE 391 MB).
// Tile loop identical to verified round 14. Merge is register-light:
// weights recomputed per (hh, r) on wave 0 (transient w8[8]).
// grid: 512 = 8 batches (low bits, XCD affinity) x 64 row-tiles, paired so
// co-resident blocks sum to 33 tile-units.
// ---------------------------------------------------------------------------
__global__ __launch_bounds__(512, 2) void attn_mfma(
    const u16* __restrict__ qg,
    const u16* __restrict__ kg,
    const u16* __restrict__ vtg,
    float* __restrict__ out)
{
    // Pool: loop phase  = Plds u16[8][32][72]             = 36864 B
    //       merge phase = Om f32[512][17] (34816 B) @0
    //                   + Ms f32[512][8]  (16384 B) @34816
    //                   + Ls f32[512][8]  (16384 B) @51200  -> 67584 B
    __shared__ __align__(16) unsigned char Pool[67584];
    u16 (*Plds)[32][72] = reinterpret_cast<u16 (*)[32][72]>(Pool);

    const int tid  = threadIdx.x;
    const int wave = tid >> 6;           // 0..7
    const int lane = tid & 63;
    const int l15  = lane & 15;
    const int g    = lane >> 4;          // 0..3

    const int b   = blockIdx.x & 7;              // batch -> XCD affinity
    const int p   = blockIdx.x >> 3;             // 0..63
    const int jt  = (p < 32) ? (63 - p) : (p - 32);  // balanced CU pairing
    const int qw0 = jt * 32;                     // block's 32 q rows
    const size_t gbase = (size_t)b * TH_;

    // Q fragments: 2 row-fragments x 4 k-steps (same rows for all 8 waves)
    bf16x8 qf[2][4];
    #pragma unroll
    for (int m = 0; m < 2; ++m)
        #pragma unroll
        for (int ks = 0; ks < 4; ++ks)
            qf[m][ks] = *reinterpret_cast<const bf16x8*>(
                &qg[gbase + (size_t)(qw0 + m * 16 + l15) * H_ + ks * 32 + g * 8]);

    f32x4 oacc[2][8];
    #pragma unroll
    for (int m = 0; m < 2; ++m)
        #pragma unroll
        for (int ht = 0; ht < 8; ++ht) oacc[m][ht] = (f32x4){0.f, 0.f, 0.f, 0.f};
    float m_r[2][4], lsum[2][4];
    #pragma unroll
    for (int m = 0; m < 2; ++m)
        #pragma unroll
        for (int r = 0; r < 4; ++r) { m_r[m][r] = -INFINITY; lsum[m][r] = 0.f; }

    const u16* kbat  = kg  + gbase;
    const u16* vtbat = vtg + gbase;

    const int nt = (jt >> 1) + 1;        // causal s-tiles for this row-tile
    for (int st = wave; st < nt; st += 8) {
        const int s0 = st * 64;
        const u16* kp = kbat + (size_t)s0 * H_;

        // ---- batch-issue 16 K loads via asm (back-to-back, no interleaved waits)
        bf16x8 kf[4][4];
        #pragma unroll
        for (int ks = 0; ks < 4; ++ks)
            #pragma unroll
            for (int t4 = 0; t4 < 4; ++t4) {
                const u16* pk = &kp[(size_t)(t4 * 16 + l15) * H_ + (ks * 4 + g) * 8];
                asm volatile("global_load_dwordx4 %0, %1, off"
                             : "=v"(kf[ks][t4]) : "v"(pk));
            }
        asm volatile("s_waitcnt vmcnt(0)" ::: "memory");
        __builtin_amdgcn_sched_barrier(0);

        // ---- QK^T: 32 MFMA (2 m x 4 ks x 4 t4), K reused across m ----
        f32x4 sa[2][4];
        #pragma unroll
        for (int m = 0; m < 2; ++m)
            #pragma unroll
            for (int t4 = 0; t4 < 4; ++t4) sa[m][t4] = (f32x4){0.f, 0.f, 0.f, 0.f};
        __builtin_amdgcn_s_setprio(1);
        #pragma unroll
        for (int ks = 0; ks < 4; ++ks)
            #pragma unroll
            for (int t4 = 0; t4 < 4; ++t4)
                #pragma unroll
                for (int m = 0; m < 2; ++m)
                    sa[m][t4] = __builtin_amdgcn_mfma_f32_16x16x32_bf16(
                        qf[m][ks], kf[ks][t4], sa[m][t4], 0, 0, 0);
        __builtin_amdgcn_s_setprio(0);

        // ---- batch-issue 16 V loads via asm (V0 then V1); fly under softmax --
        bf16x8 vf0[8], vf1[8];
        #pragma unroll
        for (int ht = 0; ht < 8; ++ht) {
            const u16* pv = &vtbat[(size_t)(ht * 16 + l15) * T_ + s0 + g * 8];
            asm volatile("global_load_dwordx4 %0, %1, off"
                         : "=v"(vf0[ht]) : "v"(pv));
        }
        #pragma unroll
        for (int ht = 0; ht < 8; ++ht) {
            const u16* pv = &vtbat[(size_t)(ht * 16 + l15) * T_ + s0 + (4 + g) * 8];
            asm volatile("global_load_dwordx4 %0, %1, off"
                         : "=v"(vf1[ht]) : "v"(pv));
        }

        // ---- online softmax over 8 rows/lane (2 m x 4 r) ----
        const float scale = 0.088388347648318447f;   // 1/sqrt(128)
        const bool need_mask = (s0 + 63 > qw0);
        float cfac[2][4];
        #pragma unroll
        for (int m = 0; m < 2; ++m) {
            #pragma unroll
            for (int r = 0; r < 4; ++r) {
                const int qrow = qw0 + m * 16 + g * 4 + r;
                float sv[4];
                float mx = -INFINITY;
                #pragma unroll
                for (int t4 = 0; t4 < 4; ++t4) {
                    float s = sa[m][t4][r] * scale;
                    if (need_mask && (s0 + t4 * 16 + l15 > qrow)) s = -INFINITY;
                    sv[t4] = s;
                    mx = fmaxf(mx, s);
                }
                mx = fmaxf(mx, __shfl_xor(mx, 1));
                mx = fmaxf(mx, __shfl_xor(mx, 2));
                mx = fmaxf(mx, __shfl_xor(mx, 4));
                mx = fmaxf(mx, __shfl_xor(mx, 8));
                const float mn = fmaxf(m_r[m][r], mx);
                const float c  = __expf(m_r[m][r] - mn);
                float sum = 0.f;
                #pragma unroll
                for (int t4 = 0; t4 < 4; ++t4) {
                    float pv = __expf(sv[t4] - mn);
                    sum += pv;
                    Plds[wave][m * 16 + g * 4 + r][t4 * 16 + l15] = f2bf(pv);
                }
                sum += __shfl_xor(sum, 1);
                sum += __shfl_xor(sum, 2);
                sum += __shfl_xor(sum, 4);
                sum += __shfl_xor(sum, 8);
                lsum[m][r] = lsum[m][r] * c + sum;
                m_r[m][r]  = mn;
                cfac[m][r] = c;
            }
        }

        // ---- rescale O ----
        #pragma unroll
        for (int m = 0; m < 2; ++m)
            #pragma unroll
            for (int ht = 0; ht < 8; ++ht)
                #pragma unroll
                for (int r = 0; r < 4; ++r) oacc[m][ht][r] *= cfac[m][r];

        // ---- PV half 0: wait V0 only (vmcnt(8) keeps V1 outstanding) ----
        asm volatile("s_waitcnt vmcnt(8)" ::: "memory");
        __builtin_amdgcn_sched_barrier(0);
        #pragma unroll
        for (int m = 0; m < 2; ++m) {
            bf16x8 pa = *reinterpret_cast<const bf16x8*>(
                &Plds[wave][m * 16 + l15][g * 8]);
            __builtin_amdgcn_s_setprio(1);
            #pragma unroll
            for (int ht = 0; ht < 8; ++ht)
                oacc[m][ht] = __builtin_amdgcn_mfma_f32_16x16x32_bf16(
                    pa, vf0[ht], oacc[m][ht], 0, 0, 0);
            __builtin_amdgcn_s_setprio(0);
        }
        // ---- PV half 1 ----
        asm volatile("s_waitcnt vmcnt(0)" ::: "memory");
        __builtin_amdgcn_sched_barrier(0);
        #pragma unroll
        for (int m = 0; m < 2; ++m) {
            bf16x8 pa = *reinterpret_cast<const bf16x8*>(
                &Plds[wave][m * 16 + l15][32 + g * 8]);
            __builtin_amdgcn_s_setprio(1);
            #pragma unroll
            for (int ht = 0; ht < 8; ++ht)
                oacc[m][ht] = __builtin_amdgcn_mfma_f32_16x16x32_bf16(
                    pa, vf1[ht], oacc[m][ht], 0, 0, 0);
            __builtin_amdgcn_s_setprio(0);
        }
    }

    // ---- block-wide 8-partial split-s merge, 2 m x 2 ht-half passes ----
    __syncthreads();                      // all waves done with Plds -> pool reuse
    {
        float* Om = reinterpret_cast<float*>(Pool);           // [512][17]
        float* Ms = reinterpret_cast<float*>(Pool + 34816);   // [512][8]
        float* Ls = reinterpret_cast<float*>(Pool + 51200);   // [512][8]
        const int wl = wave * 64 + lane;
        #pragma unroll
        for (int m = 0; m < 2; ++m)
            #pragma unroll
            for (int r = 0; r < 4; ++r) {
                Ms[wl * 8 + m * 4 + r] = m_r[m][r];
                Ls[wl * 8 + m * 4 + r] = lsum[m][r];
            }

        #pragma unroll
        for (int m = 0; m < 2; ++m) {
            float Mr[4], inv[4];          // persists across the two ht-halves
            #pragma unroll
            for (int hh = 0; hh < 2; ++hh) {
                #pragma unroll
                for (int h4 = 0; h4 < 4; ++h4)
                    #pragma unroll
                    for (int r = 0; r < 4; ++r)
                        Om[wl * 17 + h4 * 4 + r] = oacc[m][hh * 4 + h4][r];
                __syncthreads();

                if (wave == 0) {
                    if (hh == 0) {
                        #pragma unroll
                        for (int r = 0; r < 4; ++r) {
                            float M = -INFINITY;
                            #pragma unroll
                            for (int w2 = 0; w2 < 8; ++w2)
                                M = fmaxf(M, Ms[(w2 * 64 + lane) * 8 + m * 4 + r]);
                            float L = 0.f;
                            #pragma unroll
                            for (int w2 = 0; w2 < 8; ++w2)
                                L += Ls[(w2 * 64 + lane) * 8 + m * 4 + r] *
                                     __expf(Ms[(w2 * 64 + lane) * 8 + m * 4 + r] - M);
                            Mr[r]  = M;
                            inv[r] = 1.f / L;
                        }
                    }
                    #pragma unroll
                    for (int r = 0; r < 4; ++r) {
                        float w8[8];      // transient per (hh, r)
                        #pragma unroll
                        for (int w2 = 0; w2 < 8; ++w2)
                            w8[w2] = __expf(
                                Ms[(w2 * 64 + lane) * 8 + m * 4 + r] - Mr[r]);
                        float* op = &out[gbase +
                            (size_t)(qw0 + m * 16 + g * 4 + r) * H_];
                        #pragma unroll
                        for (int h4 = 0; h4 < 4; ++h4) {
                            float a = 0.f;
                            #pragma unroll
                            for (int w2 = 0; w2 < 8; ++w2)
                                a += Om[(w2 * 64 + lane) * 17 + h4 * 4 + r]
                                     * w8[w2];
                            op[(hh * 4 + h4) * 16 + l15] = a * inv[r];
                        }
                    }
                }
                __syncthreads();          // wave0 done reading Om before overwrite
            }
        }
    }
}

// ---------------------------------------------------------------------------
extern "C" void kernel_launch(void* const* d_in, const int* in_sizes, int n_in,
                              void* d_out, int out_size, void* d_ws, size_t ws_size,
                              hipStream_t stream) {
    const float* x  = (const float*)d_in[0];
    const float* Wk = (const float*)d_in[1];
    const float* Wq = (const float*)d_in[2];
    const float* Wv = (const float*)d_in[3];
    float* out = (float*)d_out;

    u16* k_ws  = (u16*)d_ws;
    u16* q_ws  = k_ws + (size_t)BT_ * H_;
    u16* vt_ws = q_ws + (size_t)BT_ * H_;
    u16* Wt_ws = vt_ws + (size_t)BT_ * H_;

    prep_kernel<<<dim3(24), 256, 0, stream>>>(Wk, Wq, Wv, Wt_ws);

    dim3 pgrid(BT_ / 64, 1, 3);    // z: 0=k, 1=q, 2=v^T
    proj_mfma<<<pgrid, 256, 0, stream>>>(x, Wt_ws, k_ws, q_ws, vt_ws);

    attn_mfma<<<dim3(512), 512, 0, stream>>>(q_ws, k_ws, vt_ws, out);
}

// Round 17
// 72.946 us; speedup vs baseline: 2.4784x; 1.3661x over previous
//
#include <hip/hip_runtime.h>
#include <hip/hip_bf16.h>
#include <math.h>

#define B_  8
#define T_  2048
#define E_  1024
#define H_  128
#define BT_ (B_*T_)
#define TH_ (T_*H_)

typedef unsigned short u16;
typedef __attribute__((ext_vector_type(8))) unsigned short u16x8;  // 16B
typedef __attribute__((ext_vector_type(8))) short bf16x8;          // MFMA A/B frag
typedef __attribute__((ext_vector_type(4))) float f32x4;           // MFMA C/D frag

__device__ __forceinline__ u16 f2bf(float f) {
    union { float f; unsigned int u; } a;
    a.f = f;
    unsigned int r = a.u + 0x7FFFu + ((a.u >> 16) & 1u);   // RNE
    return (u16)(r >> 16);
}

// ---------------------------------------------------------------------------
// prep: W[e][h] fp32  ->  Wt[w][h][e] bf16   (verified round 5)
// ---------------------------------------------------------------------------
__global__ __launch_bounds__(256) void prep_kernel(
    const float* __restrict__ Wk,
    const float* __restrict__ Wq,
    const float* __restrict__ Wv,
    u16* __restrict__ Wt)
{
    __shared__ u16 Tl[128][136];

    const int w  = blockIdx.x >> 3;
    const int et = blockIdx.x & 7;
    const float* __restrict__ W = (w == 0) ? Wk : (w == 1) ? Wq : Wv;
    const int tid = threadIdx.x;

    #pragma unroll
    for (int i = 0; i < 16; ++i) {
        int q = tid + i * 256;
        int e = q >> 5, hc = q & 31;
        float4 v = *reinterpret_cast<const float4*>(
            &W[(size_t)(et * 128 + e) * H_ + hc * 4]);
        Tl[hc * 4 + 0][e] = f2bf(v.x);
        Tl[hc * 4 + 1][e] = f2bf(v.y);
        Tl[hc * 4 + 2][e] = f2bf(v.z);
        Tl[hc * 4 + 3][e] = f2bf(v.w);
    }
    __syncthreads();

    #pragma unroll
    for (int i = 0; i < 8; ++i) {
        int q = tid + i * 256;
        int h = q >> 4, ec = q & 15;
        *reinterpret_cast<u16x8*>(
            &Wt[(size_t)w * (H_ * E_) + (size_t)h * E_ + et * 128 + ec * 8]) =
            *reinterpret_cast<const u16x8*>(&Tl[h][ec * 8]);
    }
}

// ---------------------------------------------------------------------------
// proj_mfma: out[t][h] = x[t][:] . W[:,h]  via bf16 MFMA (verified round 5)
// ---------------------------------------------------------------------------
__global__ __launch_bounds__(256) void proj_mfma(
    const float* __restrict__ x,
    const u16* __restrict__ Wt,
    u16* __restrict__ k_out,
    u16* __restrict__ q_out,
    u16* __restrict__ vt_out)
{
    __shared__ __align__(16) u16 S[13824];   // As[64][72] @0 | Bs[128][72] @4608
    u16* As = S;
    u16* Bs = S + 4608;

    const int row0 = blockIdx.x * 64;
    const int w    = blockIdx.z;
    const int tid  = threadIdx.x;
    const int wave = tid >> 6;
    const int lane = tid & 63;
    const int l15  = lane & 15;
    const int g    = lane >> 4;
    const int wm   = wave >> 1;
    const int wn   = wave & 1;

    f32x4 acc[2][4];
    #pragma unroll
    for (int m = 0; m < 2; ++m)
        #pragma unroll
        for (int n = 0; n < 4; ++n) acc[m][n] = (f32x4){0.f, 0.f, 0.f, 0.f};

    const u16* WtW = Wt + (size_t)w * (H_ * E_);

    for (int ek = 0; ek < 16; ++ek) {
        __syncthreads();
        #pragma unroll
        for (int i = 0; i < 4; ++i) {
            int q = tid + i * 256;
            int r = q >> 4, c4 = q & 15;
            float4 v = *reinterpret_cast<const float4*>(
                &x[(size_t)(row0 + r) * E_ + ek * 64 + c4 * 4]);
            ushort4 h4;
            h4.x = f2bf(v.x); h4.y = f2bf(v.y);
            h4.z = f2bf(v.z); h4.w = f2bf(v.w);
            *reinterpret_cast<ushort4*>(&As[r * 72 + c4 * 4]) = h4;
        }
        #pragma unroll
        for (int i = 0; i < 4; ++i) {
            int q = tid + i * 256;
            int h = q >> 3, c8 = q & 7;
            *reinterpret_cast<u16x8*>(&Bs[h * 72 + c8 * 8]) =
                *reinterpret_cast<const u16x8*>(
                    &WtW[(size_t)h * E_ + ek * 64 + c8 * 8]);
        }
        __syncthreads();

        #pragma unroll
        for (int kk = 0; kk < 2; ++kk) {
            bf16x8 af[2];
            #pragma unroll
            for (int m = 0; m < 2; ++m)
                af[m] = *reinterpret_cast<const bf16x8*>(
                    &As[(wm * 32 + m * 16 + l15) * 72 + kk * 32 + g * 8]);
            #pragma unroll
            for (int n = 0; n < 4; ++n) {
                bf16x8 bfr = *reinterpret_cast<const bf16x8*>(
                    &Bs[(wn * 64 + n * 16 + l15) * 72 + kk * 32 + g * 8]);
                #pragma unroll
                for (int m = 0; m < 2; ++m)
                    acc[m][n] = __builtin_amdgcn_mfma_f32_16x16x32_bf16(
                        af[m], bfr, acc[m][n], 0, 0, 0);
            }
        }
    }
    __syncthreads();

    if (w < 2) {
        #pragma unroll
        for (int m = 0; m < 2; ++m)
            #pragma unroll
            for (int n = 0; n < 4; ++n)
                #pragma unroll
                for (int r = 0; r < 4; ++r)
                    S[(wm * 32 + m * 16 + g * 4 + r) * 136 +
                      wn * 64 + n * 16 + l15] = f2bf(acc[m][n][r]);
        __syncthreads();
        u16* __restrict__ outp = (w == 0) ? k_out : q_out;
        #pragma unroll
        for (int i = 0; i < 4; ++i) {
            int q = tid + i * 256;
            int r = q >> 4, c8 = q & 15;
            *reinterpret_cast<u16x8*>(
                &outp[(size_t)(row0 + r) * H_ + c8 * 8]) =
                *reinterpret_cast<const u16x8*>(&S[r * 136 + c8 * 8]);
        }
    } else {
        #pragma unroll
        for (int m = 0; m < 2; ++m)
            #pragma unroll
            for (int n = 0; n < 4; ++n) {
                ushort4 h4;
                h4.x = f2bf(acc[m][n][0]); h4.y = f2bf(acc[m][n][1]);
                h4.z = f2bf(acc[m][n][2]); h4.w = f2bf(acc[m][n][3]);
                *reinterpret_cast<ushort4*>(
                    &S[(wn * 64 + n * 16 + l15) * 72 +
                       wm * 32 + m * 16 + g * 4]) = h4;
            }
        __syncthreads();
        const int vb = row0 >> 11;
        const int t0 = row0 & 2047;
        #pragma unroll
        for (int i = 0; i < 4; ++i) {
            int q = tid + i * 256;
            int h = q >> 3, c8 = q & 7;
            *reinterpret_cast<u16x8*>(
                &vt_out[(size_t)vb * TH_ + (size_t)h * T_ + t0 + c8 * 8]) =
                *reinterpret_cast<const u16x8*>(&S[h * 72 + c8 * 8]);
        }
    }
}

// ---------------------------------------------------------------------------
// Flash attention, bf16 MFMA — round-14 structure (4 waves, 4-way in-block
// split-s, asm-batched VMEM + counted vmcnt, balanced CU pairing) with
// SWAPPED QK^T (T12 idea): ssa = mfma(K, Q) so each lane owns ONE q-row
// (q = l15) with its 16 S-values IN REGISTERS:
//   ssa[m][t4][r] @lane(l15,g) = S[q = qw0+m*16+l15][s = s0+t4*16+g*4+r]
// Row softmax = in-register tree + 2 shuffles (xor16, xor32) instead of
// 8x depth-4 ds_bpermute chains (64 -> 8 shuffles per tile).
// P written to the VERIFIED Plds[qrow][s] layout -> PV/merge unchanged.
// cfac/lsum rebroadcast to D-layout via small LDS (explicit lgkmcnt fence).
// grid: 512 = 8 batches (XCD affinity) x 64 row-tiles, pair-balanced.
// ---------------------------------------------------------------------------
__global__ __launch_bounds__(256, 2) void attn_mfma(
    const u16* __restrict__ qg,
    const u16* __restrict__ kg,
    const u16* __restrict__ vtg,
    float* __restrict__ out)
{
    // Pool: loop phase  = Plds u16[4][32][72] (18432 B) @0
    //                   + Cl  f32[4][2][16]   (512 B)  @18432
    //       merge phase = Om  f32[256][33]    (33792 B) @0
    //                   + Msn f32[4][2][16]   (512 B)  @33792
    //                   + Lsn f32[4][2][16]   (512 B)  @34304  -> 34816 B
    __shared__ __align__(16) unsigned char Pool[34816];
    u16 (*Plds)[32][72] = reinterpret_cast<u16 (*)[32][72]>(Pool);
    float* Cl = reinterpret_cast<float*>(Pool + 18432);

    const int tid  = threadIdx.x;
    const int wave = tid >> 6;
    const int lane = tid & 63;
    const int l15  = lane & 15;
    const int g    = lane >> 4;          // 0..3

    const int b   = blockIdx.x & 7;              // batch -> XCD affinity
    const int p   = blockIdx.x >> 3;             // 0..63
    const int jt  = (p < 32) ? (63 - p) : (p - 32);  // balanced CU pairing
    const int qw0 = jt * 32;                     // block's 32 q rows
    const size_t gbase = (size_t)b * TH_;

    // Q fragments: 2 row-fragments x 4 k-steps (same rows for all 4 waves)
    bf16x8 qf[2][4];
    #pragma unroll
    for (int m = 0; m < 2; ++m)
        #pragma unroll
        for (int ks = 0; ks < 4; ++ks)
            qf[m][ks] = *reinterpret_cast<const bf16x8*>(
                &qg[gbase + (size_t)(qw0 + m * 16 + l15) * H_ + ks * 32 + g * 8]);

    f32x4 oacc[2][8];
    #pragma unroll
    for (int m = 0; m < 2; ++m)
        #pragma unroll
        for (int ht = 0; ht < 8; ++ht) oacc[m][ht] = (f32x4){0.f, 0.f, 0.f, 0.f};
    float m_r[2]  = {-INFINITY, -INFINITY};   // per-lane q-row = qw0+m*16+l15
    float lsum[2] = {0.f, 0.f};

    const u16* kbat  = kg  + gbase;
    const u16* vtbat = vtg + gbase;

    const int nt = (jt >> 1) + 1;        // causal s-tiles for this row-tile
    for (int st = wave; st < nt; st += 4) {
        const int s0 = st * 64;
        const u16* kp = kbat + (size_t)s0 * H_;

        // ---- batch-issue 16 K loads via asm ----
        bf16x8 kf[4][4];
        #pragma unroll
        for (int ks = 0; ks < 4; ++ks)
            #pragma unroll
            for (int t4 = 0; t4 < 4; ++t4) {
                const u16* pk = &kp[(size_t)(t4 * 16 + l15) * H_ + (ks * 4 + g) * 8];
                asm volatile("global_load_dwordx4 %0, %1, off"
                             : "=v"(kf[ks][t4]) : "v"(pk));
            }
        asm volatile("s_waitcnt vmcnt(0)" ::: "memory");
        __builtin_amdgcn_sched_barrier(0);

        // ---- SWAPPED QK^T: ssa = K . Q^T  (S transposed into lane-local rows)
        f32x4 ssa[2][4];
        #pragma unroll
        for (int m = 0; m < 2; ++m)
            #pragma unroll
            for (int t4 = 0; t4 < 4; ++t4) ssa[m][t4] = (f32x4){0.f, 0.f, 0.f, 0.f};
        __builtin_amdgcn_s_setprio(1);
        #pragma unroll
        for (int ks = 0; ks < 4; ++ks)
            #pragma unroll
            for (int t4 = 0; t4 < 4; ++t4)
                #pragma unroll
                for (int m = 0; m < 2; ++m)
                    ssa[m][t4] = __builtin_amdgcn_mfma_f32_16x16x32_bf16(
                        kf[ks][t4], qf[m][ks], ssa[m][t4], 0, 0, 0);
        __builtin_amdgcn_s_setprio(0);

        // ---- batch-issue 16 V loads via asm (V0 then V1); fly under softmax --
        bf16x8 vf0[8], vf1[8];
        #pragma unroll
        for (int ht = 0; ht < 8; ++ht) {
            const u16* pv = &vtbat[(size_t)(ht * 16 + l15) * T_ + s0 + g * 8];
            asm volatile("global_load_dwordx4 %0, %1, off"
                         : "=v"(vf0[ht]) : "v"(pv));
        }
        #pragma unroll
        for (int ht = 0; ht < 8; ++ht) {
            const u16* pv = &vtbat[(size_t)(ht * 16 + l15) * T_ + s0 + (4 + g) * 8];
            asm volatile("global_load_dwordx4 %0, %1, off"
                         : "=v"(vf1[ht]) : "v"(pv));
        }

        // ---- lane-local online softmax (q-row = qw0 + m*16 + l15) ----
        const float scale = 0.088388347648318447f;   // 1/sqrt(128)
        const bool need_mask = (s0 + 63 > qw0);
        #pragma unroll
        for (int m = 0; m < 2; ++m) {
            const int qrow = qw0 + m * 16 + l15;
            float sval[4][4];
            #pragma unroll
            for (int t4 = 0; t4 < 4; ++t4)
                #pragma unroll
                for (int r = 0; r < 4; ++r) {
                    float s = ssa[m][t4][r] * scale;
                    if (need_mask && (s0 + t4 * 16 + g * 4 + r > qrow))
                        s = -INFINITY;
                    sval[t4][r] = s;
                }
            float mt0 = fmaxf(fmaxf(sval[0][0], sval[0][1]),
                              fmaxf(sval[0][2], sval[0][3]));
            float mt1 = fmaxf(fmaxf(sval[1][0], sval[1][1]),
                              fmaxf(sval[1][2], sval[1][3]));
            float mt2 = fmaxf(fmaxf(sval[2][0], sval[2][1]),
                              fmaxf(sval[2][2], sval[2][3]));
            float mt3 = fmaxf(fmaxf(sval[3][0], sval[3][1]),
                              fmaxf(sval[3][2], sval[3][3]));
            float mx = fmaxf(fmaxf(mt0, mt1), fmaxf(mt2, mt3));
            mx = fmaxf(mx, __shfl_xor(mx, 16));
            mx = fmaxf(mx, __shfl_xor(mx, 32));
            const float mn = fmaxf(m_r[m], mx);
            const float c  = __expf(m_r[m] - mn);
            float sum = 0.f;
            #pragma unroll
            for (int t4 = 0; t4 < 4; ++t4) {
                float p0 = __expf(sval[t4][0] - mn);
                float p1 = __expf(sval[t4][1] - mn);
                float p2 = __expf(sval[t4][2] - mn);
                float p3 = __expf(sval[t4][3] - mn);
                sum += (p0 + p1) + (p2 + p3);
                ushort4 h4;
                h4.x = f2bf(p0); h4.y = f2bf(p1);
                h4.z = f2bf(p2); h4.w = f2bf(p3);
                *reinterpret_cast<ushort4*>(
                    &Plds[wave][m * 16 + l15][t4 * 16 + g * 4]) = h4;
            }
            sum += __shfl_xor(sum, 16);
            sum += __shfl_xor(sum, 32);
            lsum[m] = lsum[m] * c + sum;
            m_r[m]  = mn;
            Cl[(wave * 2 + m) * 16 + l15] = c;   // broadcast cfac by q-row
        }
        // fence: P + Cl writes visible before cross-lane LDS reads (rule #18)
        asm volatile("s_waitcnt lgkmcnt(0)" ::: "memory");
        __builtin_amdgcn_sched_barrier(0);

        // ---- cfac in D layout (q-row = g*4+r) and O rescale ----
        float cf[2][4];
        #pragma unroll
        for (int m = 0; m < 2; ++m)
            #pragma unroll
            for (int r = 0; r < 4; ++r)
                cf[m][r] = Cl[(wave * 2 + m) * 16 + g * 4 + r];
        #pragma unroll
        for (int m = 0; m < 2; ++m)
            #pragma unroll
            for (int ht = 0; ht < 8; ++ht)
                #pragma unroll
                for (int r = 0; r < 4; ++r) oacc[m][ht][r] *= cf[m][r];

        // ---- PV half 0: wait V0 only (vmcnt(8) keeps V1 outstanding) ----
        asm volatile("s_waitcnt vmcnt(8)" ::: "memory");
        __builtin_amdgcn_sched_barrier(0);
        #pragma unroll
        for (int m = 0; m < 2; ++m) {
            bf16x8 pa = *reinterpret_cast<const bf16x8*>(
                &Plds[wave][m * 16 + l15][g * 8]);
            __builtin_amdgcn_s_setprio(1);
            #pragma unroll
            for (int ht = 0; ht < 8; ++ht)
                oacc[m][ht] = __builtin_amdgcn_mfma_f32_16x16x32_bf16(
                    pa, vf0[ht], oacc[m][ht], 0, 0, 0);
            __builtin_amdgcn_s_setprio(0);
        }
        // ---- PV half 1 ----
        asm volatile("s_waitcnt vmcnt(0)" ::: "memory");
        __builtin_amdgcn_sched_barrier(0);
        #pragma unroll
        for (int m = 0; m < 2; ++m) {
            bf16x8 pa = *reinterpret_cast<const bf16x8*>(
                &Plds[wave][m * 16 + l15][32 + g * 8]);
            __builtin_amdgcn_s_setprio(1);
            #pragma unroll
            for (int ht = 0; ht < 8; ++ht)
                oacc[m][ht] = __builtin_amdgcn_mfma_f32_16x16x32_bf16(
                    pa, vf1[ht], oacc[m][ht], 0, 0, 0);
            __builtin_amdgcn_s_setprio(0);
        }
    }

    // ---- block-wide split-s merge through LDS, 2 m-passes ----
    __syncthreads();                      // all waves done with Plds/Cl -> reuse
    {
        float* Om  = reinterpret_cast<float*>(Pool);           // [256][33]
        float* Msn = reinterpret_cast<float*>(Pool + 33792);   // [4][2][16]
        float* Lsn = reinterpret_cast<float*>(Pool + 34304);   // [4][2][16]
        const int wl = wave * 64 + lane;
        #pragma unroll
        for (int m = 0; m < 2; ++m) {
            Msn[(wave * 2 + m) * 16 + l15] = m_r[m];   // indexed by q-row
            Lsn[(wave * 2 + m) * 16 + l15] = lsum[m];
        }

        #pragma unroll
        for (int m = 0; m < 2; ++m) {
            #pragma unroll
            for (int ht = 0; ht < 8; ++ht)
                #pragma unroll
                for (int r = 0; r < 4; ++r)
                    Om[wl * 33 + ht * 4 + r] = oacc[m][ht][r];
            __syncthreads();

            if (wave == 0) {
                #pragma unroll
                for (int r = 0; r < 4; ++r) {
                    const int row = g * 4 + r;     // q-row within m-half
                    float M = -INFINITY;
                    #pragma unroll
                    for (int w2 = 0; w2 < 4; ++w2)
                        M = fmaxf(M, Msn[(w2 * 2 + m) * 16 + row]);
                    float wgt[4];
                    float L = 0.f;
                    #pragma unroll
                    for (int w2 = 0; w2 < 4; ++w2) {
                        wgt[w2] = __expf(Msn[(w2 * 2 + m) * 16 + row] - M);
                        L += Lsn[(w2 * 2 + m) * 16 + row] * wgt[w2];
                    }
                    const float inv = 1.f / L;
                    float* op = &out[gbase + (size_t)(qw0 + m * 16 + row) * H_];
                    #pragma unroll
                    for (int ht = 0; ht < 8; ++ht) {
                        float a = 0.f;
                        #pragma unroll
                        for (int w2 = 0; w2 < 4; ++w2)
                            a += Om[(w2 * 64 + lane) * 33 + ht * 4 + r] * wgt[w2];
                        op[ht * 16 + l15] = a * inv;
                    }
                }
            }
            __syncthreads();              // wave0 done reading Om before overwrite
        }
    }
}

// ---------------------------------------------------------------------------
extern "C" void kernel_launch(void* const* d_in, const int* in_sizes, int n_in,
                              void* d_out, int out_size, void* d_ws, size_t ws_size,
                              hipStream_t stream) {
    const float* x  = (const float*)d_in[0];
    const float* Wk = (const float*)d_in[1];
    const float* Wq = (const float*)d_in[2];
    const float* Wv = (const float*)d_in[3];
    float* out = (float*)d_out;

    u16* k_ws  = (u16*)d_ws;
    u16* q_ws  = k_ws + (size_t)BT_ * H_;
    u16* vt_ws = q_ws + (size_t)BT_ * H_;
    u16* Wt_ws = vt_ws + (size_t)BT_ * H_;

    prep_kernel<<<dim3(24), 256, 0, stream>>>(Wk, Wq, Wv, Wt_ws);

    dim3 pgrid(BT_ / 64, 1, 3);    // z: 0=k, 1=q, 2=v^T
    proj_mfma<<<pgrid, 256, 0, stream>>>(x, Wt_ws, k_ws, q_ws, vt_ws);

    attn_mfma<<<dim3(512), 256, 0, stream>>>(q_ws, k_ws, vt_ws, out);
}